// Round 3
// baseline (481.583 us; speedup 1.0000x reference)
//
#include <hip/hip_runtime.h>

#define TPB 256

// ================= init: hist=0, head=-1 =================

__global__ void k_init(int* __restrict__ hist, int* __restrict__ head, int n) {
    int i = blockIdx.x * TPB + threadIdx.x;
    if (i < n) { hist[i] = 0; head[i] = -1; }
}

// ================= build per-dst linked lists + degree histogram =================
// next[e] is the ONLY bulk write and it's coalesced by e (vs 105MB scattered in R1).

__global__ void k_build(const int* __restrict__ dst, int* __restrict__ hist,
                        int* __restrict__ head, int* __restrict__ next, int E) {
    int e = blockIdx.x * TPB + threadIdx.x;
    if (e < E) {
        int d = dst[e];
        atomicAdd(&hist[d], 1);
        int old = atomicExch(&head[d], e);
        next[e] = old;
    }
}

__global__ void k_dinv(const int* __restrict__ hist, float* __restrict__ dinv, int n) {
    int i = blockIdx.x * TPB + threadIdx.x;
    if (i < n) dinv[i] = rsqrtf((float)hist[i] + 1.0f);  // +1 self-loop
}

// ================= W transpose (one-time, 64 KB) =================

__global__ void k_transpose(const float* __restrict__ W, float* __restrict__ Wt) {
    int idx = blockIdx.x * TPB + threadIdx.x;
    if (idx < 128 * 128) {
        int j = idx >> 7, k = idx & 127;
        Wt[k * 128 + j] = W[idx];
    }
}

// ================= GEMM: g[i][j] = dinv[i] * sum_k x[i][k] * W[j][k] =================

__global__ __launch_bounds__(256) void k_gemm(const float* __restrict__ x,
                                              const float* __restrict__ Wt,
                                              const float* __restrict__ dinv,
                                              float* __restrict__ g, int n) {
    __shared__ float xs[32][64];
    __shared__ float ws[64][128];
    const int tid = threadIdx.x;
    const int tx = tid & 31;
    const int ty = tid >> 5;
    const int row0 = blockIdx.x * 32;

    float acc[4][4] = {{0.f}};

    for (int kb = 0; kb < 128; kb += 64) {
        for (int i = tid; i < 32 * 16; i += 256) {
            int r = i >> 4, c4 = i & 15;
            int row = row0 + r;
            float4 v = make_float4(0.f, 0.f, 0.f, 0.f);
            if (row < n) v = *(const float4*)(x + (long)row * 128 + kb + c4 * 4);
            *(float4*)(&xs[r][c4 * 4]) = v;
        }
        for (int i = tid; i < 64 * 32; i += 256) {
            int r = i >> 5, c4 = i & 31;
            *(float4*)(&ws[r][c4 * 4]) = *(const float4*)(Wt + (long)(kb + r) * 128 + c4 * 4);
        }
        __syncthreads();

        #pragma unroll 4
        for (int k = 0; k < 64; ++k) {
            float4 wv = *(const float4*)(&ws[k][tx * 4]);
            float xr0 = xs[ty * 4 + 0][k];
            float xr1 = xs[ty * 4 + 1][k];
            float xr2 = xs[ty * 4 + 2][k];
            float xr3 = xs[ty * 4 + 3][k];
            acc[0][0] += xr0 * wv.x; acc[0][1] += xr0 * wv.y; acc[0][2] += xr0 * wv.z; acc[0][3] += xr0 * wv.w;
            acc[1][0] += xr1 * wv.x; acc[1][1] += xr1 * wv.y; acc[1][2] += xr1 * wv.z; acc[1][3] += xr1 * wv.w;
            acc[2][0] += xr2 * wv.x; acc[2][1] += xr2 * wv.y; acc[2][2] += xr2 * wv.z; acc[2][3] += xr2 * wv.w;
            acc[3][0] += xr3 * wv.x; acc[3][1] += xr3 * wv.y; acc[3][2] += xr3 * wv.z; acc[3][3] += xr3 * wv.w;
        }
        __syncthreads();
    }

    #pragma unroll
    for (int r = 0; r < 4; ++r) {
        int row = row0 + ty * 4 + r;
        if (row < n) {
            float s = dinv[row];
            float4 v = make_float4(acc[r][0] * s, acc[r][1] * s, acc[r][2] * s, acc[r][3] * s);
            *(float4*)(g + (long)row * 128 + tx * 4) = v;
        }
    }
}

// ================= aggregate via linked-list chase =================
// 32-lane group handles TWO dst rows with interleaved chains (2x ILP on the
// dependent next[] chase). All chase loads are group-uniform -> HW broadcast.

__global__ __launch_bounds__(256) void k_aggregate(const int* __restrict__ next,
                                                   const int* __restrict__ esrc,
                                                   const int* __restrict__ head,
                                                   const float* __restrict__ g,
                                                   const float* __restrict__ dinv,
                                                   const float* __restrict__ b,
                                                   float* __restrict__ out, int n) {
    int group = blockIdx.x * (TPB / 32) + (threadIdx.x >> 5);
    int d0 = group * 2;
    int d1 = d0 + 1;
    if (d0 >= n) return;
    bool has1 = (d1 < n);
    int c = (threadIdx.x & 31) << 2;

    int e0 = head[d0];
    int e1 = has1 ? head[d1] : -1;

    float4 acc0 = *(const float4*)(g + (long)d0 * 128 + c);  // self-loop message
    float4 acc1 = make_float4(0.f, 0.f, 0.f, 0.f);
    if (has1) acc1 = *(const float4*)(g + (long)d1 * 128 + c);

    // interleaved dual-chain walk
    while (e0 >= 0 && e1 >= 0) {
        int n0 = next[e0], s0 = esrc[e0];
        int n1 = next[e1], s1 = esrc[e1];
        float4 v0 = *(const float4*)(g + (long)s0 * 128 + c);
        float4 v1 = *(const float4*)(g + (long)s1 * 128 + c);
        acc0.x += v0.x; acc0.y += v0.y; acc0.z += v0.z; acc0.w += v0.w;
        acc1.x += v1.x; acc1.y += v1.y; acc1.z += v1.z; acc1.w += v1.w;
        e0 = n0; e1 = n1;
    }
    while (e0 >= 0) {
        int n0 = next[e0], s0 = esrc[e0];
        float4 v0 = *(const float4*)(g + (long)s0 * 128 + c);
        acc0.x += v0.x; acc0.y += v0.y; acc0.z += v0.z; acc0.w += v0.w;
        e0 = n0;
    }
    while (e1 >= 0) {
        int n1 = next[e1], s1 = esrc[e1];
        float4 v1 = *(const float4*)(g + (long)s1 * 128 + c);
        acc1.x += v1.x; acc1.y += v1.y; acc1.z += v1.z; acc1.w += v1.w;
        e1 = n1;
    }

    float4 bb = *(const float4*)(b + c);
    {
        float s = dinv[d0];
        float4 r;
        r.x = acc0.x * s + bb.x; r.y = acc0.y * s + bb.y;
        r.z = acc0.z * s + bb.z; r.w = acc0.w * s + bb.w;
        *(float4*)(out + (long)d0 * 128 + c) = r;
    }
    if (has1) {
        float s = dinv[d1];
        float4 r;
        r.x = acc1.x * s + bb.x; r.y = acc1.y * s + bb.y;
        r.z = acc1.z * s + bb.z; r.w = acc1.w * s + bb.w;
        *(float4*)(out + (long)d1 * 128 + c) = r;
    }
}

// ================= launch =================

extern "C" void kernel_launch(void* const* d_in, const int* in_sizes, int n_in,
                              void* d_out, int out_size, void* d_ws, size_t ws_size,
                              hipStream_t stream) {
    const float* x = (const float*)d_in[0];
    const int*   ei = (const int*)d_in[1];
    // d_in[2] = edge_attr (unused; GCN edge weight = 1)
    const float* W = (const float*)d_in[3];
    const float* b = (const float*)d_in[4];
    float* out = (float*)d_out;

    const int N = in_sizes[0] / 128;
    const int E = in_sizes[1] / 2;
    const int* src = ei;       // esrc, read in-place during aggregate
    const int* dst = ei + E;

    // ---- workspace carve (~58.9 MB) ----
    char* p = (char*)d_ws;
    auto carve = [&](size_t bytes) { char* q = p; p += (bytes + 255) & ~(size_t)255; return q; };
    int*   hist = (int*)  carve((size_t)N * 4);
    int*   head = (int*)  carve((size_t)N * 4);
    int*   next = (int*)  carve((size_t)E * 4);
    float* dinv = (float*)carve((size_t)N * 4);
    float* Wt   = (float*)carve((size_t)128 * 128 * 4);
    float* g    = (float*)carve((size_t)N * 128 * 4);

    int gridN = (N + TPB - 1) / TPB;
    int gridE = (E + TPB - 1) / TPB;

    k_init<<<gridN, TPB, 0, stream>>>(hist, head, N);
    k_build<<<gridE, TPB, 0, stream>>>(dst, hist, head, next, E);
    k_dinv<<<gridN, TPB, 0, stream>>>(hist, dinv, N);

    k_transpose<<<(128 * 128 + TPB - 1) / TPB, TPB, 0, stream>>>(W, Wt);
    k_gemm<<<(N + 31) / 32, TPB, 0, stream>>>(x, Wt, dinv, g, N);

    // 16 dst rows per block (8 groups x 2 dsts)
    int dstPerBlock = (TPB / 32) * 2;
    k_aggregate<<<(N + dstPerBlock - 1) / dstPerBlock, TPB, 0, stream>>>(
        next, src, head, g, dinv, b, out, N);
}

// Round 4
// 376.127 us; speedup vs baseline: 1.2804x; 1.2804x over previous
//
#include <hip/hip_runtime.h>

#define TPB 256

typedef __attribute__((ext_vector_type(4))) float f32x4;
typedef __attribute__((ext_vector_type(8))) short short8;

// fp32 -> bf16 with round-to-nearest-even (inputs are finite normals)
__device__ __forceinline__ unsigned short f2bf(float f) {
    unsigned u = __float_as_uint(f);
    u = (u + 0x7fffu + ((u >> 16) & 1u)) >> 16;
    return (unsigned short)u;
}
__device__ __forceinline__ float bflo(unsigned u) { return __uint_as_float(u << 16); }
__device__ __forceinline__ float bfhi(unsigned u) { return __uint_as_float(u & 0xffff0000u); }

// ================= build per-dst linked lists + degree histogram =================
// link[e] = {next, src} packed int2: ONE random line fetch per hop at walk time.
// The bulk write link[e] is coalesced by e.

__global__ void k_build(const int* __restrict__ src, const int* __restrict__ dst,
                        int* __restrict__ hist, int* __restrict__ head,
                        int2* __restrict__ link, int E) {
    int e = blockIdx.x * TPB + threadIdx.x;
    if (e < E) {
        int d = dst[e];
        atomicAdd(&hist[d], 1);
        int old = atomicExch(&head[d], e);
        link[e] = make_int2(old, src[e]);
    }
}

__global__ void k_dinv(const int* __restrict__ hist, float* __restrict__ dinv, int n) {
    int i = blockIdx.x * TPB + threadIdx.x;
    if (i < n) dinv[i] = rsqrtf((float)hist[i] + 1.0f);  // +1 self-loop
}

// ================= W fp32 -> bf16 (layout stays [out_j][k] == MFMA B[n][k]) ======

__global__ void k_castW(const float* __restrict__ W, unsigned short* __restrict__ Wt) {
    int i = blockIdx.x * TPB + threadIdx.x;
    if (i < 128 * 128) Wt[i] = f2bf(W[i]);
}

// ================= GEMM via MFMA: g[i][j] = bf16( dinv[i] * sum_k x[i][k]*W[j][k] )
// 16x16x32 bf16 MFMA. Per 64-lane wave: 16 rows x 128 cols (8 n-tiles x 4 k-steps).
// A frag: m=lane&15, k=quad*8+j  -> contiguous 8 elems of x row, converted in-reg.
// B frag: n=lane&15, k=quad*8+j  -> W[j][k] row-major, staged once in LDS.
// C/D:    col=lane&15, row=quad*4+reg.
// LDS k-pad +8 bf16: row stride 272B -> lanes l and l+8 share banks = 2-way (free).

__global__ __launch_bounds__(256) void k_gemm(const float* __restrict__ x,
                                              const unsigned short* __restrict__ Wt,
                                              const float* __restrict__ dinv,
                                              unsigned short* __restrict__ g, int n) {
    __shared__ unsigned short wb[128][136];
    const int tid = threadIdx.x;

    // stage Wt (32KB) into LDS with b128 writes: 2048 uint4 chunks
    for (int cthunk = tid; cthunk < 2048; cthunk += 256) {
        int nrow = cthunk >> 4, k8 = (cthunk & 15) << 3;
        *(uint4*)&wb[nrow][k8] = ((const uint4*)Wt)[cthunk];
    }
    __syncthreads();

    const int lane = tid & 63;
    const int wid  = tid >> 6;
    const int l15  = lane & 15;
    const int quad = lane >> 4;
    const int row  = blockIdx.x * 64 + wid * 16 + l15;
    const int rowc = (row < n) ? row : (n - 1);   // clamped load; store is guarded

    f32x4 acc[8];
    #pragma unroll
    for (int t = 0; t < 8; ++t) acc[t] = (f32x4){0.f, 0.f, 0.f, 0.f};

    #pragma unroll
    for (int ks = 0; ks < 4; ++ks) {
        const int kb = ks * 32 + quad * 8;
        float4 a0 = *(const float4*)(x + (long)rowc * 128 + kb);
        float4 a1 = *(const float4*)(x + (long)rowc * 128 + kb + 4);
        union { unsigned short u[8]; short8 v; } af;
        af.u[0] = f2bf(a0.x); af.u[1] = f2bf(a0.y); af.u[2] = f2bf(a0.z); af.u[3] = f2bf(a0.w);
        af.u[4] = f2bf(a1.x); af.u[5] = f2bf(a1.y); af.u[6] = f2bf(a1.z); af.u[7] = f2bf(a1.w);
        #pragma unroll
        for (int t = 0; t < 8; ++t) {
            short8 bf = *(const short8*)&wb[t * 16 + l15][kb];
            acc[t] = __builtin_amdgcn_mfma_f32_16x16x32_bf16(af.v, bf, acc[t], 0, 0, 0);
        }
    }

    int   orow[4];
    float dv[4];
    #pragma unroll
    for (int r = 0; r < 4; ++r) {
        orow[r] = blockIdx.x * 64 + wid * 16 + quad * 4 + r;
        dv[r]   = (orow[r] < n) ? dinv[orow[r]] : 0.f;
    }
    #pragma unroll
    for (int t = 0; t < 8; ++t) {
        int col = t * 16 + l15;
        #pragma unroll
        for (int r = 0; r < 4; ++r) {
            if (orow[r] < n)
                g[(long)orow[r] * 128 + col] = f2bf(acc[t][r] * dv[r]);
        }
    }
}

// ================= aggregate via dual linked-list chase, bf16 gathers ============
// 32-lane group handles TWO dst rows (2x ILP on the dependent chase). Each lane
// covers 4 bf16 (8B) of the 256B row. fp32 accumulate; epilogue dinv[d]*acc + b.

__global__ __launch_bounds__(256) void k_aggregate(const int2* __restrict__ link,
                                                   const int* __restrict__ head,
                                                   const unsigned short* __restrict__ g,
                                                   const float* __restrict__ dinv,
                                                   const float* __restrict__ b,
                                                   float* __restrict__ out, int n) {
    int group = blockIdx.x * (TPB / 32) + (threadIdx.x >> 5);
    int d0 = group * 2, d1 = d0 + 1;
    if (d0 >= n) return;
    bool has1 = (d1 < n);
    int c = (threadIdx.x & 31) << 2;  // starting bf16 column, 4 per lane

    float4 acc0 = make_float4(0.f, 0.f, 0.f, 0.f);
    float4 acc1 = make_float4(0.f, 0.f, 0.f, 0.f);

    auto loadrow = [&](int r, float4& acc) {
        uint2 p = *(const uint2*)(g + (long)r * 128 + c);
        acc.x += bflo(p.x); acc.y += bfhi(p.x);
        acc.z += bflo(p.y); acc.w += bfhi(p.y);
    };

    loadrow(d0, acc0);              // self-loop message (dinv[d] already folded in g)
    if (has1) loadrow(d1, acc1);

    int e0 = head[d0];
    int e1 = has1 ? head[d1] : -1;

    while (e0 >= 0 && e1 >= 0) {
        int2 l0 = link[e0];
        int2 l1 = link[e1];
        loadrow(l0.y, acc0);
        loadrow(l1.y, acc1);
        e0 = l0.x; e1 = l1.x;
    }
    while (e0 >= 0) { int2 l0 = link[e0]; loadrow(l0.y, acc0); e0 = l0.x; }
    while (e1 >= 0) { int2 l1 = link[e1]; loadrow(l1.y, acc1); e1 = l1.x; }

    float4 bb = *(const float4*)(b + c);
    {
        float s = dinv[d0];
        float4 r = make_float4(acc0.x * s + bb.x, acc0.y * s + bb.y,
                               acc0.z * s + bb.z, acc0.w * s + bb.w);
        *(float4*)(out + (long)d0 * 128 + c) = r;
    }
    if (has1) {
        float s = dinv[d1];
        float4 r = make_float4(acc1.x * s + bb.x, acc1.y * s + bb.y,
                               acc1.z * s + bb.z, acc1.w * s + bb.w);
        *(float4*)(out + (long)d1 * 128 + c) = r;
    }
}

// ================= launch =================

extern "C" void kernel_launch(void* const* d_in, const int* in_sizes, int n_in,
                              void* d_out, int out_size, void* d_ws, size_t ws_size,
                              hipStream_t stream) {
    const float* x  = (const float*)d_in[0];
    const int*   ei = (const int*)d_in[1];
    // d_in[2] = edge_attr (unused; GCN edge weight = 1)
    const float* W  = (const float*)d_in[3];
    const float* b  = (const float*)d_in[4];
    float* out = (float*)d_out;

    const int N = in_sizes[0] / 128;
    const int E = in_sizes[1] / 2;
    const int* src = ei;
    const int* dst = ei + E;

    // ---- workspace carve (~39.6 MB) ----
    char* p = (char*)d_ws;
    auto carve = [&](size_t bytes) { char* q = p; p += (bytes + 255) & ~(size_t)255; return q; };
    int*            hist = (int*)           carve((size_t)N * 4);
    int*            head = (int*)           carve((size_t)N * 4);
    int2*           link = (int2*)          carve((size_t)E * 8);
    float*          dinv = (float*)         carve((size_t)N * 4);
    unsigned short* Wt   = (unsigned short*)carve((size_t)128 * 128 * 2);
    unsigned short* g    = (unsigned short*)carve((size_t)N * 128 * 2);

    int gridN = (N + TPB - 1) / TPB;
    int gridE = (E + TPB - 1) / TPB;

    hipMemsetAsync(hist, 0,    (size_t)N * 4, stream);
    hipMemsetAsync(head, 0xFF, (size_t)N * 4, stream);  // head[i] = -1

    k_build<<<gridE, TPB, 0, stream>>>(src, dst, hist, head, link, E);
    k_dinv<<<gridN, TPB, 0, stream>>>(hist, dinv, N);
    k_castW<<<(128 * 128 + TPB - 1) / TPB, TPB, 0, stream>>>(W, Wt);

    k_gemm<<<(N + 63) / 64, TPB, 0, stream>>>(x, Wt, dinv, g, N);

    int dstPerBlock = (TPB / 32) * 2;  // 16 dsts per block
    k_aggregate<<<(N + dstPerBlock - 1) / dstPerBlock, TPB, 0, stream>>>(
        link, head, g, dinv, b, out, N);
}

// Round 5
// 319.301 us; speedup vs baseline: 1.5082x; 1.1780x over previous
//
#include <hip/hip_runtime.h>

#define TPB 256

typedef __attribute__((ext_vector_type(4))) float f32x4;
typedef __attribute__((ext_vector_type(8))) short short8;

// fp32 -> bf16 round-to-nearest-even
__device__ __forceinline__ unsigned short f2bf(float f) {
    unsigned u = __float_as_uint(f);
    u = (u + 0x7fffu + ((u >> 16) & 1u)) >> 16;
    return (unsigned short)u;
}
__device__ __forceinline__ float bflo(unsigned u) { return __uint_as_float(u << 16); }
__device__ __forceinline__ float bfhi(unsigned u) { return __uint_as_float(u & 0xffff0000u); }

// ================= build per-dst linked lists (ONLY atomic: exch) ==============
// link[e] = {next, src}; coalesced bulk write. Degree is derived later by walking
// chains (saves 1.6M memory-side atomicAdds vs R3).

__global__ void k_build(const int* __restrict__ src, const int* __restrict__ dst,
                        int* __restrict__ head, int2* __restrict__ link, int E) {
    int stride = gridDim.x * TPB;
    for (int e = blockIdx.x * TPB + threadIdx.x; e < E; e += stride) {
        int d = dst[e];
        int old = atomicExch(&head[d], e);
        link[e] = make_int2(old, src[e]);
    }
}

// ================= chain walk #1: degree -> dinv =================

__global__ void k_count(const int* __restrict__ head, const int2* __restrict__ link,
                        int* __restrict__ deg, float* __restrict__ dinv, int n) {
    int d = blockIdx.x * TPB + threadIdx.x;
    if (d >= n) return;
    int e = head[d];
    int c = 0;
    while (e >= 0) { c++; e = link[e].x; }
    deg[d] = c;
    dinv[d] = rsqrtf((float)c + 1.0f);  // +1 self-loop
}

// ================= exclusive scan of deg (512-elem blocks) =================

__global__ __launch_bounds__(512) void k_scan1(const int* __restrict__ deg,
                                               int* __restrict__ incl,
                                               int* __restrict__ bsum, int n) {
    __shared__ int tmp[2][512];
    int t = threadIdx.x;
    int i = blockIdx.x * 512 + t;
    int v = (i < n) ? deg[i] : 0;
    tmp[0][t] = v;
    __syncthreads();
    int sb = 0;
    for (int d = 1; d < 512; d <<= 1) {
        int val = tmp[sb][t];
        if (t >= d) val += tmp[sb][t - d];
        tmp[sb ^ 1][t] = val;
        sb ^= 1;
        __syncthreads();
    }
    int inc = tmp[sb][t];
    if (i < n) incl[i] = inc;
    if (t == 511) bsum[blockIdx.x] = inc;
}

__global__ __launch_bounds__(256) void k_scan2(int* __restrict__ bsum, int nb) {
    __shared__ int tmp[2][256];
    int t = threadIdx.x;
    int v = (t < nb) ? bsum[t] : 0;
    tmp[0][t] = v;
    __syncthreads();
    int sb = 0;
    for (int d = 1; d < 256; d <<= 1) {
        int val = tmp[sb][t];
        if (t >= d) val += tmp[sb][t - d];
        tmp[sb ^ 1][t] = val;
        sb ^= 1;
        __syncthreads();
    }
    if (t < nb) bsum[t] = tmp[sb][t] - v;  // exclusive
}

__global__ void k_scan3(const int* __restrict__ incl, const int* __restrict__ deg,
                        const int* __restrict__ bsum, int* __restrict__ offsets,
                        int n, int E) {
    int i = blockIdx.x * TPB + threadIdx.x;
    if (i < n) offsets[i] = incl[i] - deg[i] + bsum[i >> 9];
    else if (i == n) offsets[n] = E;
}

// ================= chain walk #2: emit CSR (contiguous writes per dst) ==========

__global__ void k_csr(const int* __restrict__ head, const int2* __restrict__ link,
                      const int* __restrict__ offsets, int* __restrict__ sorted_src,
                      int n) {
    int d = blockIdx.x * TPB + threadIdx.x;
    if (d >= n) return;
    int e = head[d];
    int off = offsets[d];
    while (e >= 0) {
        int2 l = link[e];
        sorted_src[off++] = l.y;
        e = l.x;
    }
}

// ================= W fp32 -> bf16 =================

__global__ void k_castW(const float* __restrict__ W, unsigned short* __restrict__ Wt) {
    int i = blockIdx.x * TPB + threadIdx.x;
    if (i < 128 * 128) Wt[i] = f2bf(W[i]);
}

// ================= GEMM via MFMA: g[i][j] = bf16( dinv[i] * sum_k x[i][k]*W[j][k] )

__global__ __launch_bounds__(256) void k_gemm(const float* __restrict__ x,
                                              const unsigned short* __restrict__ Wt,
                                              const float* __restrict__ dinv,
                                              unsigned short* __restrict__ g, int n) {
    __shared__ unsigned short wb[128][136];
    const int tid = threadIdx.x;

    for (int chunk = tid; chunk < 2048; chunk += 256) {
        int nrow = chunk >> 4, k8 = (chunk & 15) << 3;
        *(uint4*)&wb[nrow][k8] = ((const uint4*)Wt)[chunk];
    }
    __syncthreads();

    const int lane = tid & 63;
    const int wid  = tid >> 6;
    const int l15  = lane & 15;
    const int quad = lane >> 4;
    const int row  = blockIdx.x * 64 + wid * 16 + l15;
    const int rowc = (row < n) ? row : (n - 1);

    f32x4 acc[8];
    #pragma unroll
    for (int t = 0; t < 8; ++t) acc[t] = (f32x4){0.f, 0.f, 0.f, 0.f};

    #pragma unroll
    for (int ks = 0; ks < 4; ++ks) {
        const int kb = ks * 32 + quad * 8;
        float4 a0 = *(const float4*)(x + (long)rowc * 128 + kb);
        float4 a1 = *(const float4*)(x + (long)rowc * 128 + kb + 4);
        union { unsigned short u[8]; short8 v; } af;
        af.u[0] = f2bf(a0.x); af.u[1] = f2bf(a0.y); af.u[2] = f2bf(a0.z); af.u[3] = f2bf(a0.w);
        af.u[4] = f2bf(a1.x); af.u[5] = f2bf(a1.y); af.u[6] = f2bf(a1.z); af.u[7] = f2bf(a1.w);
        #pragma unroll
        for (int t = 0; t < 8; ++t) {
            short8 bf = *(const short8*)&wb[t * 16 + l15][kb];
            acc[t] = __builtin_amdgcn_mfma_f32_16x16x32_bf16(af.v, bf, acc[t], 0, 0, 0);
        }
    }

    int   orow[4];
    float dv[4];
    #pragma unroll
    for (int r = 0; r < 4; ++r) {
        orow[r] = blockIdx.x * 64 + wid * 16 + quad * 4 + r;
        dv[r]   = (orow[r] < n) ? dinv[orow[r]] : 0.f;
    }
    #pragma unroll
    for (int t = 0; t < 8; ++t) {
        int col = t * 16 + l15;
        #pragma unroll
        for (int r = 0; r < 4; ++r) {
            if (orow[r] < n)
                g[(long)orow[r] * 128 + col] = f2bf(acc[t][r] * dv[r]);
        }
    }
}

// ================= CSR aggregate: out[d] = dinv[d]*(g[d] + sum g[src]) + b ======
// 32 lanes per dst; lane covers 4 bf16 (8B); 4-wide unrolled independent gathers.

__global__ __launch_bounds__(256) void k_aggregate(const int* __restrict__ sorted_src,
                                                   const int* __restrict__ offsets,
                                                   const unsigned short* __restrict__ g,
                                                   const float* __restrict__ dinv,
                                                   const float* __restrict__ b,
                                                   float* __restrict__ out, int n) {
    int d = blockIdx.x * (TPB / 32) + (threadIdx.x >> 5);
    if (d >= n) return;
    int c = (threadIdx.x & 31) << 2;  // bf16 column

    int s0 = offsets[d];
    int s1 = offsets[d + 1];

    float4 acc = make_float4(0.f, 0.f, 0.f, 0.f);
    auto addrow = [&](int r) {
        uint2 p = *(const uint2*)(g + (long)r * 128 + c);
        acc.x += bflo(p.x); acc.y += bfhi(p.x);
        acc.z += bflo(p.y); acc.w += bfhi(p.y);
    };

    addrow(d);  // self-loop
    int e = s0;
    for (; e + 4 <= s1; e += 4) {
        int a0 = sorted_src[e + 0];
        int a1 = sorted_src[e + 1];
        int a2 = sorted_src[e + 2];
        int a3 = sorted_src[e + 3];
        addrow(a0); addrow(a1); addrow(a2); addrow(a3);
    }
    for (; e < s1; ++e) addrow(sorted_src[e]);

    float s = dinv[d];
    float4 bb = *(const float4*)(b + c);
    float4 r = make_float4(acc.x * s + bb.x, acc.y * s + bb.y,
                           acc.z * s + bb.z, acc.w * s + bb.w);
    *(float4*)(out + (long)d * 128 + c) = r;
}

// ================= launch =================

extern "C" void kernel_launch(void* const* d_in, const int* in_sizes, int n_in,
                              void* d_out, int out_size, void* d_ws, size_t ws_size,
                              hipStream_t stream) {
    const float* x  = (const float*)d_in[0];
    const int*   ei = (const int*)d_in[1];
    // d_in[2] = edge_attr (unused; GCN edge weight = 1)
    const float* W  = (const float*)d_in[3];
    const float* b  = (const float*)d_in[4];
    float* out = (float*)d_out;

    const int N = in_sizes[0] / 128;
    const int E = in_sizes[1] / 2;
    const int* src = ei;
    const int* dst = ei + E;

    const int NB512 = (N + 511) / 512;  // 196 <= 256

    // ---- workspace carve (~47 MB) ----
    char* p = (char*)d_ws;
    auto carve = [&](size_t bytes) { char* q = p; p += (bytes + 255) & ~(size_t)255; return q; };
    int*            head       = (int*)           carve((size_t)N * 4);
    int2*           link       = (int2*)          carve((size_t)E * 8);
    int*            deg        = (int*)           carve((size_t)N * 4);
    float*          dinv       = (float*)         carve((size_t)N * 4);
    int*            incl       = (int*)           carve((size_t)N * 4);
    int*            bsum       = (int*)           carve(1024 * 4);
    int*            offsets    = (int*)           carve((size_t)(N + 1) * 4);
    int*            sorted_src = (int*)           carve((size_t)E * 4);
    unsigned short* Wt         = (unsigned short*)carve((size_t)128 * 128 * 2);
    unsigned short* g          = (unsigned short*)carve((size_t)N * 128 * 2);

    int gridN = (N + TPB - 1) / TPB;

    hipMemsetAsync(head, 0xFF, (size_t)N * 4, stream);  // head = -1

    k_build<<<(E / 4 + TPB - 1) / TPB, TPB, 0, stream>>>(src, dst, head, link, E);
    k_count<<<gridN, TPB, 0, stream>>>(head, link, deg, dinv, N);

    k_scan1<<<NB512, 512, 0, stream>>>(deg, incl, bsum, N);
    k_scan2<<<1, 256, 0, stream>>>(bsum, NB512);
    k_scan3<<<(N + 1 + TPB - 1) / TPB, TPB, 0, stream>>>(incl, deg, bsum, offsets, N, E);

    k_csr<<<gridN, TPB, 0, stream>>>(head, link, offsets, sorted_src, N);

    k_castW<<<(128 * 128 + TPB - 1) / TPB, TPB, 0, stream>>>(W, Wt);
    k_gemm<<<(N + 63) / 64, TPB, 0, stream>>>(x, Wt, dinv, g, N);

    k_aggregate<<<(N + (TPB / 32) - 1) / (TPB / 32), TPB, 0, stream>>>(
        sorted_src, offsets, g, dinv, b, out, N);
}

// Round 6
// 254.570 us; speedup vs baseline: 1.8918x; 1.2543x over previous
//
#include <hip/hip_runtime.h>

#define TPB 256
#define NBLK 256          // blocks for edge-streaming kernels
#define BSH 8             // dst >> 8 -> bucket; 256 dsts per bucket

typedef __attribute__((ext_vector_type(4))) float f32x4;
typedef __attribute__((ext_vector_type(8))) short short8;

__device__ __forceinline__ unsigned short f2bf(float f) {
    unsigned u = __float_as_uint(f);
    u = (u + 0x7fffu + ((u >> 16) & 1u)) >> 16;
    return (unsigned short)u;
}
__device__ __forceinline__ float bflo(unsigned u) { return __uint_as_float(u << 16); }
__device__ __forceinline__ float bfhi(unsigned u) { return __uint_as_float(u & 0xffff0000u); }

// ============ pass A: coarse bucket histogram (LDS-aggregated) ============

__global__ __launch_bounds__(256) void k_bhist(const int* __restrict__ dst,
                                               int* __restrict__ btotal, int E, int NB) {
    __shared__ int sh[512];
    for (int i = threadIdx.x; i < NB; i += 256) sh[i] = 0;
    __syncthreads();
    int chunk = (E + NBLK - 1) / NBLK;
    int lo = blockIdx.x * chunk;
    int hi = min(E, lo + chunk);
    for (int e = lo + threadIdx.x; e < hi; e += 256)
        atomicAdd(&sh[dst[e] >> BSH], 1);
    __syncthreads();
    for (int i = threadIdx.x; i < NB; i += 256)
        if (sh[i]) atomicAdd(&btotal[i], sh[i]);   // fire-and-forget
}

// ============ pass B: scan bucket totals (1 block) ============

__global__ __launch_bounds__(512) void k_bscan(const int* __restrict__ btotal,
                                               int* __restrict__ bbase, int* __restrict__ bcur,
                                               int* __restrict__ offsets, int E, int NB, int N) {
    __shared__ int tmp[2][512];
    int t = threadIdx.x;
    int v = (t < NB) ? btotal[t] : 0;
    tmp[0][t] = v;
    __syncthreads();
    int sb = 0;
    for (int d = 1; d < 512; d <<= 1) {
        int val = tmp[sb][t];
        if (t >= d) val += tmp[sb][t - d];
        tmp[sb ^ 1][t] = val;
        sb ^= 1;
        __syncthreads();
    }
    int excl = tmp[sb][t] - v;
    if (t < NB) { bbase[t] = excl; bcur[t] = excl; }
    if (t == 0) { bbase[NB] = E; offsets[N] = E; }
}

// ============ pass C: scatter edges into bucket regions ============
// One returning atomic per (block,bucket) reserves a contiguous run; edge
// writes land in ~128B runs instead of fully scattered 4B stores.

__global__ __launch_bounds__(256) void k_bscatter(const int* __restrict__ src,
                                                  const int* __restrict__ dst,
                                                  int* __restrict__ bcur,
                                                  int2* __restrict__ pairs, int E, int NB) {
    __shared__ int sh[512];
    __shared__ int sbase[512];
    for (int i = threadIdx.x; i < NB; i += 256) sh[i] = 0;
    __syncthreads();
    int chunk = (E + NBLK - 1) / NBLK;
    int lo = blockIdx.x * chunk;
    int hi = min(E, lo + chunk);
    for (int e = lo + threadIdx.x; e < hi; e += 256)
        atomicAdd(&sh[dst[e] >> BSH], 1);
    __syncthreads();
    for (int i = threadIdx.x; i < NB; i += 256) {
        int c = sh[i];
        sbase[i] = c ? atomicAdd(&bcur[i], c) : 0;
    }
    __syncthreads();
    for (int i = threadIdx.x; i < NB; i += 256) sh[i] = sbase[i];
    __syncthreads();
    for (int e = lo + threadIdx.x; e < hi; e += 256) {
        int d = dst[e];
        int pos = atomicAdd(&sh[d >> BSH], 1);    // LDS atomic
        pairs[pos] = make_int2(d, src[e]);
    }
}

// ============ pass D: per-bucket exact CSR + offsets + dinv ============
// Block b exclusively owns dsts [b*256, b*256+256) and its edge region.

__global__ __launch_bounds__(256) void k_bcsr(const int2* __restrict__ pairs,
                                              const int* __restrict__ bbase,
                                              int* __restrict__ offsets,
                                              int* __restrict__ sorted_src,
                                              float* __restrict__ dinv, int N) {
    __shared__ int hist[256];
    __shared__ int tmp[2][256];
    __shared__ int scur[256];
    int b = blockIdx.x;
    int s0 = bbase[b], s1 = bbase[b + 1];
    int t = threadIdx.x;
    hist[t] = 0;
    __syncthreads();
    for (int e = s0 + t; e < s1; e += 256)
        atomicAdd(&hist[pairs[e].x & 255], 1);    // LDS atomic
    __syncthreads();
    int v = hist[t];
    tmp[0][t] = v;
    __syncthreads();
    int sb = 0;
    for (int d = 1; d < 256; d <<= 1) {
        int val = tmp[sb][t];
        if (t >= d) val += tmp[sb][t - d];
        tmp[sb ^ 1][t] = val;
        sb ^= 1;
        __syncthreads();
    }
    int gbase = s0 + (tmp[sb][t] - v);
    scur[t] = gbase;
    int d = (b << BSH) + t;
    if (d < N) { offsets[d] = gbase; dinv[d] = rsqrtf((float)v + 1.0f); }
    __syncthreads();
    for (int e = s0 + t; e < s1; e += 256) {
        int2 pr = pairs[e];
        int pos = atomicAdd(&scur[pr.x & 255], 1);  // LDS atomic
        sorted_src[pos] = pr.y;
    }
}

// ============ W fp32 -> bf16 ============

__global__ void k_castW(const float* __restrict__ W, unsigned short* __restrict__ Wt) {
    int i = blockIdx.x * TPB + threadIdx.x;
    if (i < 128 * 128) Wt[i] = f2bf(W[i]);
}

// ============ GEMM via MFMA: g[i][j] = bf16( dinv[i] * sum_k x[i][k]*W[j][k] ) ====

__global__ __launch_bounds__(256) void k_gemm(const float* __restrict__ x,
                                              const unsigned short* __restrict__ Wt,
                                              const float* __restrict__ dinv,
                                              unsigned short* __restrict__ g, int n) {
    __shared__ unsigned short wb[128][136];
    const int tid = threadIdx.x;

    for (int chunk = tid; chunk < 2048; chunk += 256) {
        int nrow = chunk >> 4, k8 = (chunk & 15) << 3;
        *(uint4*)&wb[nrow][k8] = ((const uint4*)Wt)[chunk];
    }
    __syncthreads();

    const int lane = tid & 63;
    const int wid  = tid >> 6;
    const int l15  = lane & 15;
    const int quad = lane >> 4;
    const int row  = blockIdx.x * 64 + wid * 16 + l15;
    const int rowc = (row < n) ? row : (n - 1);

    f32x4 acc[8];
    #pragma unroll
    for (int t = 0; t < 8; ++t) acc[t] = (f32x4){0.f, 0.f, 0.f, 0.f};

    #pragma unroll
    for (int ks = 0; ks < 4; ++ks) {
        const int kb = ks * 32 + quad * 8;
        float4 a0 = *(const float4*)(x + (long)rowc * 128 + kb);
        float4 a1 = *(const float4*)(x + (long)rowc * 128 + kb + 4);
        union { unsigned short u[8]; short8 v; } af;
        af.u[0] = f2bf(a0.x); af.u[1] = f2bf(a0.y); af.u[2] = f2bf(a0.z); af.u[3] = f2bf(a0.w);
        af.u[4] = f2bf(a1.x); af.u[5] = f2bf(a1.y); af.u[6] = f2bf(a1.z); af.u[7] = f2bf(a1.w);
        #pragma unroll
        for (int t = 0; t < 8; ++t) {
            short8 bf = *(const short8*)&wb[t * 16 + l15][kb];
            acc[t] = __builtin_amdgcn_mfma_f32_16x16x32_bf16(af.v, bf, acc[t], 0, 0, 0);
        }
    }

    int   orow[4];
    float dv[4];
    #pragma unroll
    for (int r = 0; r < 4; ++r) {
        orow[r] = blockIdx.x * 64 + wid * 16 + quad * 4 + r;
        dv[r]   = (orow[r] < n) ? dinv[orow[r]] : 0.f;
    }
    #pragma unroll
    for (int t = 0; t < 8; ++t) {
        int col = t * 16 + l15;
        #pragma unroll
        for (int r = 0; r < 4; ++r) {
            if (orow[r] < n)
                g[(long)orow[r] * 128 + col] = f2bf(acc[t][r] * dv[r]);
        }
    }
}

// ============ CSR aggregate: out[d] = dinv[d]*(g[d] + sum g[src]) + b ============
// 32 lanes per dst; 8/4/1 unroll ladder for outstanding gathers.

__global__ __launch_bounds__(256) void k_aggregate(const int* __restrict__ sorted_src,
                                                   const int* __restrict__ offsets,
                                                   const unsigned short* __restrict__ g,
                                                   const float* __restrict__ dinv,
                                                   const float* __restrict__ b,
                                                   float* __restrict__ out, int n) {
    int d = blockIdx.x * (TPB / 32) + (threadIdx.x >> 5);
    if (d >= n) return;
    int c = (threadIdx.x & 31) << 2;

    int s0 = offsets[d];
    int s1 = offsets[d + 1];

    float4 acc = make_float4(0.f, 0.f, 0.f, 0.f);
    auto addrow = [&](int r) {
        uint2 p = *(const uint2*)(g + (long)r * 128 + c);
        acc.x += bflo(p.x); acc.y += bfhi(p.x);
        acc.z += bflo(p.y); acc.w += bfhi(p.y);
    };

    addrow(d);  // self-loop
    int e = s0;
    for (; e + 8 <= s1; e += 8) {
        int a[8];
        #pragma unroll
        for (int j = 0; j < 8; ++j) a[j] = sorted_src[e + j];
        #pragma unroll
        for (int j = 0; j < 8; ++j) addrow(a[j]);
    }
    for (; e + 4 <= s1; e += 4) {
        int a[4];
        #pragma unroll
        for (int j = 0; j < 4; ++j) a[j] = sorted_src[e + j];
        #pragma unroll
        for (int j = 0; j < 4; ++j) addrow(a[j]);
    }
    for (; e < s1; ++e) addrow(sorted_src[e]);

    float s = dinv[d];
    float4 bb = *(const float4*)(b + c);
    float4 r = make_float4(acc.x * s + bb.x, acc.y * s + bb.y,
                           acc.z * s + bb.z, acc.w * s + bb.w);
    *(float4*)(out + (long)d * 128 + c) = r;
}

// ============ launch ============

extern "C" void kernel_launch(void* const* d_in, const int* in_sizes, int n_in,
                              void* d_out, int out_size, void* d_ws, size_t ws_size,
                              hipStream_t stream) {
    const float* x  = (const float*)d_in[0];
    const int*   ei = (const int*)d_in[1];
    // d_in[2] = edge_attr (unused; GCN edge weight = 1)
    const float* W  = (const float*)d_in[3];
    const float* b  = (const float*)d_in[4];
    float* out = (float*)d_out;

    const int N = in_sizes[0] / 128;
    const int E = in_sizes[1] / 2;
    const int* src = ei;
    const int* dst = ei + E;
    const int NB = (N + 255) >> BSH;   // 391 buckets (must be <= 512)

    // ---- workspace carve (~45.7 MB) ----
    char* p = (char*)d_ws;
    auto carve = [&](size_t bytes) { char* q = p; p += (bytes + 255) & ~(size_t)255; return q; };
    int*            btotal     = (int*)           carve(512 * 4);
    int*            bbase      = (int*)           carve(513 * 4);
    int*            bcur       = (int*)           carve(512 * 4);
    int*            offsets    = (int*)           carve((size_t)(N + 1) * 4);
    float*          dinv       = (float*)         carve((size_t)N * 4);
    int2*           pairs      = (int2*)          carve((size_t)E * 8);
    int*            sorted_src = (int*)           carve((size_t)E * 4);
    unsigned short* Wt         = (unsigned short*)carve((size_t)128 * 128 * 2);
    unsigned short* g          = (unsigned short*)carve((size_t)N * 128 * 2);

    hipMemsetAsync(btotal, 0, 512 * 4, stream);

    k_bhist   <<<NBLK, TPB, 0, stream>>>(dst, btotal, E, NB);
    k_bscan   <<<1, 512, 0, stream>>>(btotal, bbase, bcur, offsets, E, NB, N);
    k_bscatter<<<NBLK, TPB, 0, stream>>>(src, dst, bcur, pairs, E, NB);
    k_bcsr    <<<NB, TPB, 0, stream>>>(pairs, bbase, offsets, sorted_src, dinv, N);

    k_castW<<<(128 * 128 + TPB - 1) / TPB, TPB, 0, stream>>>(W, Wt);
    k_gemm<<<(N + 63) / 64, TPB, 0, stream>>>(x, Wt, dinv, g, N);

    k_aggregate<<<(N + (TPB / 32) - 1) / (TPB / 32), TPB, 0, stream>>>(
        sorted_src, offsets, g, dinv, b, out, N);
}